// Round 1
// baseline (293.172 us; speedup 1.0000x reference)
//
#include <hip/hip_runtime.h>
#include <hip/hip_fp16.h>
#include <math.h>

typedef _Float16 f16;
typedef __attribute__((ext_vector_type(8))) _Float16 f16x8;
typedef __attribute__((ext_vector_type(4))) _Float16 f16x4;
typedef __attribute__((ext_vector_type(4))) float f32x4;

#define NB 16
#define NN 2048
#define ND 256
#define KVB 32
#define QB 64

__global__ __launch_bounds__(256, 2)
void attn_fwd(const float* __restrict__ X,
              const int* __restrict__ lenp,
              float* __restrict__ out)
{
    const int b   = blockIdx.y;
    const int qt  = blockIdx.x;
    const int tid = threadIdx.x;
    const int lane = tid & 63;
    const int w = tid >> 6;      // wave 0..3
    const int g = lane >> 4;     // 16-lane group 0..3
    const int c = lane & 15;

    // length: auto-detect int64 vs int32 (lengths are in [1,2048], never 0,
    // so int32-view element [1] == 0  <=>  buffer is int64)
    long long Lb;
    if (lenp[1] == 0) Lb = ((const long long*)lenp)[b];
    else              Lb = (long long)lenp[b];

    __shared__ f16 Kl[KVB][264];   // K tile row-major [kv][d], stride 264 (528B, 2-way banks)
    __shared__ f16 Vt[ND][40];     // V tile transposed [d][kv], stride 40 (80B, balanced banks)
    __shared__ f16 Pl[4][16][40];  // per-wave P round-trip buffer

    const float* Xb = X + (size_t)b * NN * ND;

    // ---- Q fragments (held in registers for the whole kv loop) ----
    // A-frag: row = lane&15 -> q row qt*QB + w*16 + c ; k = kk*32 + g*8 + i
    f16x8 qf[8];
    {
        const float* qp = Xb + (size_t)(qt*QB + w*16 + c) * ND + g*8;
        #pragma unroll
        for (int kk = 0; kk < 8; ++kk) {
            float4 a = *(const float4*)(qp + kk*32);
            float4 d = *(const float4*)(qp + kk*32 + 4);
            f16x8 v;
            v[0]=(f16)a.x; v[1]=(f16)a.y; v[2]=(f16)a.z; v[3]=(f16)a.w;
            v[4]=(f16)d.x; v[5]=(f16)d.y; v[6]=(f16)d.z; v[7]=(f16)d.w;
            qf[kk] = v;
        }
    }

    f32x4 o[16];
    #pragma unroll
    for (int dt = 0; dt < 16; ++dt) o[dt] = (f32x4){0.f,0.f,0.f,0.f};
    float m[4] = {-INFINITY,-INFINITY,-INFINITY,-INFINITY};
    float l[4] = {0.f,0.f,0.f,0.f};

    const int ntiles = (int)((Lb + KVB - 1) / KVB);
    for (int t = 0; t < ntiles; ++t) {
        const int kv0 = t * KVB;
        __syncthreads();   // previous iteration's LDS consumers done

        // ---- stage K tile: 32x256 fp32 -> f16, coalesced float4 reads ----
        #pragma unroll
        for (int it = 0; it < 8; ++it) {
            int idx4 = it*256 + tid;
            int row  = idx4 >> 6;       // 64 float4 per row
            int c4   = idx4 & 63;
            float4 v = *(const float4*)(Xb + (size_t)(kv0 + row)*ND + c4*4);
            f16x4 h; h[0]=(f16)v.x; h[1]=(f16)v.y; h[2]=(f16)v.z; h[3]=(f16)v.w;
            *(f16x4*)&Kl[row][c4*4] = h;
        }
        // ---- stage Vt: thread owns column d = tid; coalesced per kv row ----
        {
            const float* cp = Xb + (size_t)kv0*ND + tid;
            #pragma unroll
            for (int kq = 0; kq < 8; ++kq) {
                f16x4 h;
                #pragma unroll
                for (int u = 0; u < 4; ++u) h[u] = (f16)cp[(size_t)(kq*4+u)*ND];
                *(f16x4*)&Vt[tid][kq*4] = h;
            }
        }
        __syncthreads();

        // ---- QK^T: S[16q x 32j] as two 16x16 tiles, K-dim 256 = 8 mfma ----
        f32x4 s0 = (f32x4){0.f,0.f,0.f,0.f};
        f32x4 s1 = (f32x4){0.f,0.f,0.f,0.f};
        #pragma unroll
        for (int kk = 0; kk < 8; ++kk) {
            f16x8 b0 = *(const f16x8*)&Kl[c     ][kk*32 + g*8];
            f16x8 b1 = *(const f16x8*)&Kl[16 + c][kk*32 + g*8];
            s0 = __builtin_amdgcn_mfma_f32_16x16x32_f16(qf[kk], b0, s0, 0, 0, 0);
            s1 = __builtin_amdgcn_mfma_f32_16x16x32_f16(qf[kk], b1, s1, 0, 0, 0);
        }

        // ---- column mask (j >= L) ----
        const float NEG = -1e30f;
        if (kv0 + c >= Lb)      { s0[0]=NEG; s0[1]=NEG; s0[2]=NEG; s0[3]=NEG; }
        if (kv0 + 16 + c >= Lb) { s1[0]=NEG; s1[1]=NEG; s1[2]=NEG; s1[3]=NEG; }

        // ---- online softmax: rows = g*4+r, reduce across 16 lanes of group ----
        float mx[4], mn[4], sc[4], p0[4], p1[4], rs[4];
        #pragma unroll
        for (int r = 0; r < 4; ++r) mx[r] = fmaxf(s0[r], s1[r]);
        #pragma unroll
        for (int off = 8; off >= 1; off >>= 1) {
            #pragma unroll
            for (int r = 0; r < 4; ++r)
                mx[r] = fmaxf(mx[r], __shfl_xor(mx[r], off, 64));
        }
        #pragma unroll
        for (int r = 0; r < 4; ++r) {
            mn[r] = fmaxf(m[r], mx[r]);
            sc[r] = __expf(m[r] - mn[r]);      // m=-inf first tile -> 0
            p0[r] = __expf(s0[r] - mn[r]);     // masked: exp(-1e30) -> 0
            p1[r] = __expf(s1[r] - mn[r]);
            rs[r] = p0[r] + p1[r];
        }
        #pragma unroll
        for (int off = 8; off >= 1; off >>= 1) {
            #pragma unroll
            for (int r = 0; r < 4; ++r)
                rs[r] += __shfl_xor(rs[r], off, 64);
        }
        bool chg = (sc[0]!=1.f) | (sc[1]!=1.f) | (sc[2]!=1.f) | (sc[3]!=1.f);
        if (__any(chg)) {
            #pragma unroll
            for (int dt = 0; dt < 16; ++dt) {
                o[dt][0]*=sc[0]; o[dt][1]*=sc[1]; o[dt][2]*=sc[2]; o[dt][3]*=sc[3];
            }
        }
        #pragma unroll
        for (int r = 0; r < 4; ++r) {
            l[r] = l[r]*sc[r] + rs[r];
            m[r] = mn[r];
        }

        // ---- P round-trip through per-wave LDS (C-layout -> A-layout) ----
        #pragma unroll
        for (int r = 0; r < 4; ++r) {
            Pl[w][g*4+r][c]      = (f16)p0[r];
            Pl[w][g*4+r][16 + c] = (f16)p1[r];
        }
        f16x8 pf = *(const f16x8*)&Pl[w][c][g*8];   // same-wave write->read, lgkmcnt ordered

        // ---- PV: O[16q x 256d] += P(16x32) * V(32x16) per d-tile ----
        #pragma unroll
        for (int dt = 0; dt < 16; ++dt) {
            f16x8 vf = *(const f16x8*)&Vt[dt*16 + c][g*8];
            o[dt] = __builtin_amdgcn_mfma_f32_16x16x32_f16(pf, vf, o[dt], 0, 0, 0);
        }
    }

    // ---- epilogue: divide by l, store fp32 ----
    float inv[4];
    #pragma unroll
    for (int r = 0; r < 4; ++r) inv[r] = 1.0f / l[r];
    float* ob = out + ((size_t)b*NN + (size_t)(qt*QB + w*16 + g*4))*ND + c;
    #pragma unroll
    for (int r = 0; r < 4; ++r) {
        #pragma unroll
        for (int dt = 0; dt < 16; ++dt)
            ob[(size_t)r*ND + dt*16] = o[dt][r] * inv[r];
    }
}

extern "C" void kernel_launch(void* const* d_in, const int* in_sizes, int n_in,
                              void* d_out, int out_size, void* d_ws, size_t ws_size,
                              hipStream_t stream) {
    const float* X    = (const float*)d_in[0];
    const int*   lenp = (const int*)d_in[1];
    float*       out  = (float*)d_out;
    dim3 grid(NN / QB, NB);
    dim3 block(256);
    hipLaunchKernelGGL(attn_fwd, grid, block, 0, stream, X, lenp, out);
}

// Round 2
// 169.995 us; speedup vs baseline: 1.7246x; 1.7246x over previous
//
#include <hip/hip_runtime.h>
#include <hip/hip_fp16.h>
#include <math.h>

typedef _Float16 f16;
typedef __attribute__((ext_vector_type(8))) _Float16 f16x8;
typedef __attribute__((ext_vector_type(4))) _Float16 f16x4;
typedef __attribute__((ext_vector_type(4))) float f32x4;

#define NB 16
#define NN 2048
#define ND 256
#define KVB 32
#define QB 64

__device__ __forceinline__ void gll16(const void* g, void* l) {
    __builtin_amdgcn_global_load_lds(
        (const __attribute__((address_space(1))) unsigned int*)g,
        (__attribute__((address_space(3))) unsigned int*)l, 16, 0, 0);
}

__device__ __forceinline__ long long get_len(const int* lenp, int b) {
    // int64 vs int32 auto-detect: lengths in [1,2048] never 0, so
    // int32-view element [1]==0  <=>  buffer is int64
    if (lenp[1] == 0) return ((const long long*)lenp)[b];
    return (long long)lenp[b];
}

// ---------------- pre-pass: X fp32 -> Xh f16 [b][n][d] + Xt f16 [b][d][n] ----
__global__ __launch_bounds__(256)
void prep(const float* __restrict__ X, f16* __restrict__ Xh, f16* __restrict__ Xt)
{
    const int b  = blockIdx.z;
    const int n0 = blockIdx.x * 64;
    const int d0 = blockIdx.y * 64;
    const int t  = threadIdx.x;
    __shared__ f16 T[64][72];

    const float* Xb  = X  + ((size_t)b*NN + n0)*ND + d0;
    f16*         Xhb = Xh + ((size_t)b*NN + n0)*ND + d0;
    #pragma unroll
    for (int it = 0; it < 4; ++it) {
        int r  = it*16 + (t >> 4);
        int c4 = t & 15;
        float4 v = *(const float4*)(Xb + (size_t)r*ND + c4*4);
        f16x4 h; h[0]=(f16)v.x; h[1]=(f16)v.y; h[2]=(f16)v.z; h[3]=(f16)v.w;
        *(f16x4*)&Xhb[(size_t)r*ND + c4*4] = h;
        *(f16x4*)&T[r][c4*4] = h;
    }
    __syncthreads();
    f16* Xtb = Xt + ((size_t)b*ND + d0)*NN + n0;
    #pragma unroll
    for (int it = 0; it < 2; ++it) {
        int id = it*256 + t;
        int dr = id >> 3;
        int ch = id & 7;
        f16x8 v;
        #pragma unroll
        for (int u = 0; u < 8; ++u) v[u] = T[ch*8+u][dr];
        *(f16x8*)&Xtb[(size_t)dr*NN + ch*8] = v;
    }
}

// ---------------- main flash-attention kernel ----------------
__global__ __launch_bounds__(256, 2)
void attn2(const f16* __restrict__ Xh, const f16* __restrict__ Xt,
           const int* __restrict__ lenp, float* __restrict__ out)
{
    // dispatch remap: first 128 blocks cover qt 0..7 of ALL batches (balance),
    // XCD bits (lin&7) track qt not batch
    const int lin = blockIdx.x;
    const int qt  = ((lin >> 7) << 3) | (lin & 7);
    const int b   = (lin >> 3) & 15;

    const int tid  = threadIdx.x;
    const int lane = tid & 63;
    const int w = tid >> 6;
    const int g = lane >> 4;
    const int c = lane & 15;

    const long long Lb = get_len(lenp, b);

    __shared__ f16 Kl[2][KVB][ND];    // linear (global_load_lds), XOR-swizzled content
    __shared__ f16 Vt[2][ND][40];     // transposed V, padded stride 40 (80B)
    __shared__ f16 Pl[4][16][40];     // per-wave P round-trip

    const char* xhb = (const char*)(Xh + (size_t)b*NN*ND);
    const f16*  xtb = Xt + (size_t)b*ND*NN;

    // ---- Q fragments in registers ----
    f16x8 qf[8];
    {
        const f16* qp = (const f16*)xhb + (size_t)(qt*QB + w*16 + c)*ND + g*8;
        #pragma unroll
        for (int kk = 0; kk < 8; ++kk) qf[kk] = *(const f16x8*)(qp + kk*32);
    }

    f32x4 o[16];
    #pragma unroll
    for (int dt = 0; dt < 16; ++dt) o[dt] = (f32x4){0.f,0.f,0.f,0.f};
    float m[4] = {-INFINITY,-INFINITY,-INFINITY,-INFINITY};
    float l[4] = {0.f,0.f,0.f,0.f};

    f16x8 vr[4];

    // K tile stage: linear LDS dest, source address inverse-XOR-swizzled
    auto stage_k = [&](int buf, int kv0) {
        char* kb = (char*)&Kl[buf][0][0];
        #pragma unroll
        for (int it = 0; it < 4; ++it) {
            int slot = (it*256 + tid) * 16;
            int kv   = slot >> 9;
            int off  = slot & 511;
            gll16(xhb + (((size_t)kv0 + kv) << 9) + (size_t)(off ^ ((kv & 7) << 4)),
                  kb + slot);
        }
    };
    auto load_v = [&](int kv0) {
        #pragma unroll
        for (int it = 0; it < 4; ++it) {
            int dr = it*64 + (tid >> 2);
            vr[it] = *(const f16x8*)(xtb + (size_t)dr*NN + kv0 + (tid & 3)*8);
        }
    };
    auto write_v = [&](int buf) {
        #pragma unroll
        for (int it = 0; it < 4; ++it) {
            int dr = it*64 + (tid >> 2);
            *(f16x8*)&Vt[buf][dr][(tid & 3)*8] = vr[it];
        }
    };

    auto compute = [&](int buf, int kv0) {
        const char* kb = (const char*)&Kl[buf][0][0];
        const int swz = (c & 7) << 4;           // (row&7)<<4, same for rows c and 16+c
        f32x4 s0 = (f32x4){0.f,0.f,0.f,0.f};
        f32x4 s1 = (f32x4){0.f,0.f,0.f,0.f};
        #pragma unroll
        for (int kk = 0; kk < 8; ++kk) {
            f16x8 b0 = *(const f16x8*)(kb + c*512      + ((kk*64 + g*16) ^ swz));
            f16x8 b1 = *(const f16x8*)(kb + (16+c)*512 + ((kk*64 + g*16) ^ swz));
            s0 = __builtin_amdgcn_mfma_f32_16x16x32_f16(qf[kk], b0, s0, 0, 0, 0);
            s1 = __builtin_amdgcn_mfma_f32_16x16x32_f16(qf[kk], b1, s1, 0, 0, 0);
        }

        const float NEG = -1e30f;
        if (kv0 + c >= Lb)      { s0[0]=NEG; s0[1]=NEG; s0[2]=NEG; s0[3]=NEG; }
        if (kv0 + 16 + c >= Lb) { s1[0]=NEG; s1[1]=NEG; s1[2]=NEG; s1[3]=NEG; }

        float mx[4], mn[4], sc[4], p0[4], p1[4], rs[4];
        #pragma unroll
        for (int r = 0; r < 4; ++r) mx[r] = fmaxf(s0[r], s1[r]);
        #pragma unroll
        for (int off = 8; off >= 1; off >>= 1) {
            #pragma unroll
            for (int r = 0; r < 4; ++r)
                mx[r] = fmaxf(mx[r], __shfl_xor(mx[r], off, 64));
        }
        #pragma unroll
        for (int r = 0; r < 4; ++r) {
            mn[r] = fmaxf(m[r], mx[r]);
            sc[r] = __expf(m[r] - mn[r]);
            p0[r] = __expf(s0[r] - mn[r]);
            p1[r] = __expf(s1[r] - mn[r]);
            rs[r] = p0[r] + p1[r];
        }
        #pragma unroll
        for (int off = 8; off >= 1; off >>= 1) {
            #pragma unroll
            for (int r = 0; r < 4; ++r)
                rs[r] += __shfl_xor(rs[r], off, 64);
        }
        bool chg = (sc[0]!=1.f) | (sc[1]!=1.f) | (sc[2]!=1.f) | (sc[3]!=1.f);
        if (__any(chg)) {
            #pragma unroll
            for (int dt = 0; dt < 16; ++dt) {
                o[dt][0]*=sc[0]; o[dt][1]*=sc[1]; o[dt][2]*=sc[2]; o[dt][3]*=sc[3];
            }
        }
        #pragma unroll
        for (int r = 0; r < 4; ++r) { l[r] = l[r]*sc[r] + rs[r]; m[r] = mn[r]; }

        #pragma unroll
        for (int r = 0; r < 4; ++r) {
            Pl[w][g*4+r][c]      = (f16)p0[r];
            Pl[w][g*4+r][16 + c] = (f16)p1[r];
        }
        f16x8 pf = *(const f16x8*)&Pl[w][c][g*8];

        #pragma unroll
        for (int dt = 0; dt < 16; ++dt) {
            f16x8 vf = *(const f16x8*)&Vt[buf][dt*16 + c][g*8];
            o[dt] = __builtin_amdgcn_mfma_f32_16x16x32_f16(pf, vf, o[dt], 0, 0, 0);
        }
    };

    const int ntiles = (int)((Lb + KVB - 1) / KVB);
    stage_k(0, 0);
    load_v(0);
    write_v(0);
    __syncthreads();
    int buf = 0;
    for (int t = 0; t < ntiles; ++t) {
        const bool pf = (t + 1 < ntiles);
        if (pf) { stage_k(buf ^ 1, (t+1)*KVB); load_v((t+1)*KVB); }
        compute(buf, t*KVB);
        if (pf) write_v(buf ^ 1);
        __syncthreads();
        buf ^= 1;
    }

    float inv[4];
    #pragma unroll
    for (int r = 0; r < 4; ++r) inv[r] = 1.0f / l[r];
    float* ob = out + ((size_t)b*NN + (size_t)(qt*QB + w*16 + g*4))*ND + c;
    #pragma unroll
    for (int r = 0; r < 4; ++r) {
        #pragma unroll
        for (int dt = 0; dt < 16; ++dt)
            ob[(size_t)r*ND + dt*16] = o[dt][r] * inv[r];
    }
}

// ---------------- fallback (round-1 kernel) if ws too small ----------------
__global__ __launch_bounds__(256, 2)
void attn_fb(const float* __restrict__ X,
             const int* __restrict__ lenp,
             float* __restrict__ out)
{
    const int b   = blockIdx.y;
    const int qt  = blockIdx.x;
    const int tid = threadIdx.x;
    const int lane = tid & 63;
    const int w = tid >> 6;
    const int g = lane >> 4;
    const int c = lane & 15;

    const long long Lb = get_len(lenp, b);

    __shared__ f16 Kl[KVB][264];
    __shared__ f16 Vt[ND][40];
    __shared__ f16 Pl[4][16][40];

    const float* Xb = X + (size_t)b * NN * ND;

    f16x8 qf[8];
    {
        const float* qp = Xb + (size_t)(qt*QB + w*16 + c) * ND + g*8;
        #pragma unroll
        for (int kk = 0; kk < 8; ++kk) {
            float4 a = *(const float4*)(qp + kk*32);
            float4 d = *(const float4*)(qp + kk*32 + 4);
            f16x8 v;
            v[0]=(f16)a.x; v[1]=(f16)a.y; v[2]=(f16)a.z; v[3]=(f16)a.w;
            v[4]=(f16)d.x; v[5]=(f16)d.y; v[6]=(f16)d.z; v[7]=(f16)d.w;
            qf[kk] = v;
        }
    }

    f32x4 o[16];
    #pragma unroll
    for (int dt = 0; dt < 16; ++dt) o[dt] = (f32x4){0.f,0.f,0.f,0.f};
    float m[4] = {-INFINITY,-INFINITY,-INFINITY,-INFINITY};
    float l[4] = {0.f,0.f,0.f,0.f};

    const int ntiles = (int)((Lb + KVB - 1) / KVB);
    for (int t = 0; t < ntiles; ++t) {
        const int kv0 = t * KVB;
        __syncthreads();
        #pragma unroll
        for (int it = 0; it < 8; ++it) {
            int idx4 = it*256 + tid;
            int row  = idx4 >> 6;
            int c4   = idx4 & 63;
            float4 v = *(const float4*)(Xb + (size_t)(kv0 + row)*ND + c4*4);
            f16x4 h; h[0]=(f16)v.x; h[1]=(f16)v.y; h[2]=(f16)v.z; h[3]=(f16)v.w;
            *(f16x4*)&Kl[row][c4*4] = h;
        }
        {
            const float* cp = Xb + (size_t)kv0*ND + tid;
            #pragma unroll
            for (int kq = 0; kq < 8; ++kq) {
                f16x4 h;
                #pragma unroll
                for (int u = 0; u < 4; ++u) h[u] = (f16)cp[(size_t)(kq*4+u)*ND];
                *(f16x4*)&Vt[tid][kq*4] = h;
            }
        }
        __syncthreads();

        f32x4 s0 = (f32x4){0.f,0.f,0.f,0.f};
        f32x4 s1 = (f32x4){0.f,0.f,0.f,0.f};
        #pragma unroll
        for (int kk = 0; kk < 8; ++kk) {
            f16x8 b0 = *(const f16x8*)&Kl[c     ][kk*32 + g*8];
            f16x8 b1 = *(const f16x8*)&Kl[16 + c][kk*32 + g*8];
            s0 = __builtin_amdgcn_mfma_f32_16x16x32_f16(qf[kk], b0, s0, 0, 0, 0);
            s1 = __builtin_amdgcn_mfma_f32_16x16x32_f16(qf[kk], b1, s1, 0, 0, 0);
        }

        const float NEG = -1e30f;
        if (kv0 + c >= Lb)      { s0[0]=NEG; s0[1]=NEG; s0[2]=NEG; s0[3]=NEG; }
        if (kv0 + 16 + c >= Lb) { s1[0]=NEG; s1[1]=NEG; s1[2]=NEG; s1[3]=NEG; }

        float mx[4], mn[4], sc[4], p0[4], p1[4], rs[4];
        #pragma unroll
        for (int r = 0; r < 4; ++r) mx[r] = fmaxf(s0[r], s1[r]);
        #pragma unroll
        for (int off = 8; off >= 1; off >>= 1) {
            #pragma unroll
            for (int r = 0; r < 4; ++r)
                mx[r] = fmaxf(mx[r], __shfl_xor(mx[r], off, 64));
        }
        #pragma unroll
        for (int r = 0; r < 4; ++r) {
            mn[r] = fmaxf(m[r], mx[r]);
            sc[r] = __expf(m[r] - mn[r]);
            p0[r] = __expf(s0[r] - mn[r]);
            p1[r] = __expf(s1[r] - mn[r]);
            rs[r] = p0[r] + p1[r];
        }
        #pragma unroll
        for (int off = 8; off >= 1; off >>= 1) {
            #pragma unroll
            for (int r = 0; r < 4; ++r)
                rs[r] += __shfl_xor(rs[r], off, 64);
        }
        bool chg = (sc[0]!=1.f) | (sc[1]!=1.f) | (sc[2]!=1.f) | (sc[3]!=1.f);
        if (__any(chg)) {
            #pragma unroll
            for (int dt = 0; dt < 16; ++dt) {
                o[dt][0]*=sc[0]; o[dt][1]*=sc[1]; o[dt][2]*=sc[2]; o[dt][3]*=sc[3];
            }
        }
        #pragma unroll
        for (int r = 0; r < 4; ++r) { l[r] = l[r]*sc[r] + rs[r]; m[r] = mn[r]; }

        #pragma unroll
        for (int r = 0; r < 4; ++r) {
            Pl[w][g*4+r][c]      = (f16)p0[r];
            Pl[w][g*4+r][16 + c] = (f16)p1[r];
        }
        f16x8 pf = *(const f16x8*)&Pl[w][c][g*8];

        #pragma unroll
        for (int dt = 0; dt < 16; ++dt) {
            f16x8 vf = *(const f16x8*)&Vt[dt*16 + c][g*8];
            o[dt] = __builtin_amdgcn_mfma_f32_16x16x32_f16(pf, vf, o[dt], 0, 0, 0);
        }
    }

    float inv[4];
    #pragma unroll
    for (int r = 0; r < 4; ++r) inv[r] = 1.0f / l[r];
    float* ob = out + ((size_t)b*NN + (size_t)(qt*QB + w*16 + g*4))*ND + c;
    #pragma unroll
    for (int r = 0; r < 4; ++r) {
        #pragma unroll
        for (int dt = 0; dt < 16; ++dt)
            ob[(size_t)r*ND + dt*16] = o[dt][r] * inv[r];
    }
}

extern "C" void kernel_launch(void* const* d_in, const int* in_sizes, int n_in,
                              void* d_out, int out_size, void* d_ws, size_t ws_size,
                              hipStream_t stream) {
    const float* X    = (const float*)d_in[0];
    const int*   lenp = (const int*)d_in[1];
    float*       out  = (float*)d_out;

    const size_t need = (size_t)NB * NN * ND * 2 /*f16*/ * 2 /*Xh+Xt*/;
    if (ws_size >= need) {
        f16* Xh = (f16*)d_ws;
        f16* Xt = Xh + (size_t)NB * NN * ND;
        hipLaunchKernelGGL(prep, dim3(NN/64, ND/64, NB), dim3(256), 0, stream, X, Xh, Xt);
        hipLaunchKernelGGL(attn2, dim3(512), dim3(256), 0, stream, Xh, Xt, lenp, out);
    } else {
        hipLaunchKernelGGL(attn_fb, dim3(NN/QB, NB), dim3(256), 0, stream, X, lenp, out);
    }
}